// Round 13
// baseline (210.266 us; speedup 1.0000x reference)
//
#include <hip/hip_runtime.h>

#define N_USERS 100000
#define N_ITEMS 50000
#define N_NODES 150000
#define NNZ 1500000
#define BATCH 1048576
#define DIM 64

#define BIN_SHIFT 7
#define BIN_ROWS 128
#define NBINS ((N_NODES + BIN_ROWS - 1) / BIN_ROWS)    // 1172
#define NROWS_PAD (NBINS * BIN_ROWS)                   // 150016
#define CAPB 1536                                      // per-bin edge capacity (mean 1280)
#define CAPR 15                                        // bucket entries per row (128B row)
#define CAPE 8                                         // ext entries per row (covers deg<=23)
#define P1_THREADS 1024
#define EPT 4
#define EPB (P1_THREADS * EPT)                         // 4096
#define P1_BLOCKS ((NNZ + EPB - 1) / EPB)              // 367
#define CONV_N ((N_USERS + N_ITEMS) * DIM / 4)         // 2,400,000 float4/uint2 elems
#define CONV_BLOCKS ((CONV_N + 1023) / 1024)           // 2344
#define FUSED_BLOCKS 2944                              // 368 p1-role (id&7==7) + 2576 conv-role
#define G_MAX 16384
#define RARE_MAX 4096

typedef unsigned short ushortT;

__device__ __forceinline__ float bf2f(ushortT x) {
    return __uint_as_float(((unsigned)x) << 16);
}
__device__ __forceinline__ ushortT f2bf(float x) {      // RNE
    unsigned u = __float_as_uint(x);
    return (ushortT)((u + 0x7FFFu + ((u >> 16) & 1u)) >> 16);
}
__device__ __forceinline__ unsigned pack2(float a, float b) {
    unsigned ua = __float_as_uint(a), ub = __float_as_uint(b);
    ua = (ua + 0x7FFFu + ((ua >> 16) & 1u)) >> 16;
    ub = (ub + 0x7FFFu + ((ub >> 16) & 1u)) >> 16;
    return ua | (ub << 16);
}

__global__ void zero_ws(float4* __restrict__ p, int n4) {
    int i = blockIdx.x * blockDim.x + threadIdx.x;
    if (i < n4) p[i] = make_float4(0.f, 0.f, 0.f, 0.f);
}

// ---------- zero control structures (must precede fused conv+p1) ----------
__global__ void zero_ctrl(int* __restrict__ bin_cursor, int* __restrict__ g_cnt,
                          int* __restrict__ rare_cnt) {
    int i = threadIdx.x;
    for (int b = i; b < NBINS; b += 1024) bin_cursor[b] = 0;
    if (i == 0) { *g_cnt = 0; *rare_cnt = 0; }
}

// ---------- fused: conv blocks (role != 7) stream E->bf16; p1 blocks (role 7) bin edges ----------
__global__ __launch_bounds__(P1_THREADS)
void fused_conv_p1(const float4* __restrict__ Eu, const float4* __restrict__ Ei,
                   uint2* __restrict__ Eb,
                   const int* __restrict__ rows,
                   const int* __restrict__ cols,
                   const float* __restrict__ vals,
                   int* __restrict__ bin_cursor,
                   int2* __restrict__ binned,
                   int* __restrict__ g_cnt,
                   int4* __restrict__ G,
                   int* __restrict__ rare_cnt,
                   int* __restrict__ rare) {
    int tid = threadIdx.x;
    if ((blockIdx.x & 7) != 7) {
        // ---- conv role ----
        int cb = blockIdx.x - (blockIdx.x >> 3);        // conv rank
        int i = cb * 1024 + tid;
        if (i < CONV_N) {
            float4 x = (i < N_USERS * DIM / 4) ? Eu[i] : Ei[i - N_USERS * DIM / 4];
            Eb[i] = make_uint2(pack2(x.x, x.y), pack2(x.z, x.w));
        }
        return;
    }
    // ---- p1 role ----
    int pb = blockIdx.x >> 3;
    if (pb >= P1_BLOCKS) return;
    __shared__ int h[NBINS];
    __shared__ int lcnt[NBINS];
    __shared__ int lbase[NBINS + 1];
    __shared__ int2 stage[EPB];                          // 32 KB
    __shared__ ushortT sbin[EPB];                        // 8 KB
    for (int i = tid; i < NBINS; i += P1_THREADS) lcnt[i] = 0;
    __syncthreads();

    int base_e = pb * EPB;
    int re[EPT]; int ce[EPT]; float ve[EPT];
#pragma unroll
    for (int k = 0; k < EPT; ++k) {
        int e = base_e + k * P1_THREADS + tid;
        if (e < NNZ) {
            re[k] = rows[e]; ce[k] = cols[e]; ve[k] = vals[e];
            atomicAdd(&lcnt[re[k] >> BIN_SHIFT], 1);
        } else {
            re[k] = -1; ce[k] = 0; ve[k] = 0.f;
        }
    }
    __syncthreads();

    // exclusive scan lcnt -> lbase (wave 0)
    if (tid < 64) {
        int carry = 0;
        for (int b0 = 0; b0 < NBINS; b0 += 64) {
            int idx = b0 + tid;
            int x = (idx < NBINS) ? lcnt[idx] : 0;
            int incl = x;
#pragma unroll
            for (int off = 1; off < 64; off <<= 1) {
                int t = __shfl_up(incl, off);
                if (tid >= off) incl += t;
            }
            if (idx < NBINS) lbase[idx] = carry + incl - x;
            carry += __shfl(incl, 63);
        }
        if (tid == 0) lbase[NBINS] = carry;
    }
    __syncthreads();

    for (int i = tid; i < NBINS; i += P1_THREADS) {
        int c = lcnt[i];
        h[i] = (c > 0) ? atomicAdd(&bin_cursor[i], c) : 0;
        lcnt[i] = 0;
    }
    __syncthreads();

#pragma unroll
    for (int k = 0; k < EPT; ++k) {
        if (re[k] >= 0) {
            int b = re[k] >> BIN_SHIFT;
            int pos = lbase[b] + atomicAdd(&lcnt[b], 1);
            stage[pos] = make_int2((ce[k] << BIN_SHIFT) | (re[k] & (BIN_ROWS - 1)),
                                   __float_as_int(ve[k]));
            sbin[pos] = (ushortT)b;
        }
    }
    __syncthreads();

    int total = lbase[NBINS];
    for (int j = tid; j < total; j += P1_THREADS) {
        int b = sbin[j];
        int2 cv = stage[j];
        int off = h[b] + (j - lbase[b]);
        if (off < CAPB) {
            binned[(size_t)b * CAPB + off] = cv;
        } else {                                         // statistically impossible; correctness path
            int r = b * BIN_ROWS + (cv.x & (BIN_ROWS - 1));
            int c = (int)(((unsigned)cv.x) >> BIN_SHIFT);
            int p = atomicAdd(g_cnt, 1);
            if (p < G_MAX) G[p] = make_int4(r, c, cv.y, 0);
            int q = atomicAdd(rare_cnt, 1);
            if (q < RARE_MAX) rare[q] = r;
        }
    }
}

// ---------- pass 2: build 128 bucket rows (+ext) per bin in LDS ----------
// Row format (32 ints / 128 B): [cnt_full, pad, c0, v0, ..., c14, v14]
__global__ __launch_bounds__(512)
void p2_fill(const int* __restrict__ bin_cursor,
             const int2* __restrict__ binned,
             int* __restrict__ buckets,
             int2* __restrict__ ext,
             int* __restrict__ rare_cnt,
             int* __restrict__ rare) {
    __shared__ int  cnt_s[BIN_ROWS];                 // 0.5 KB
    __shared__ int2 rowbuf[BIN_ROWS * CAPR];         // 15 KB
    int bin = blockIdx.x, tid = threadIdx.x;
    for (int i = tid; i < BIN_ROWS; i += 512) cnt_s[i] = 0;
    __syncthreads();
    int n = bin_cursor[bin]; if (n > CAPB) n = CAPB;
    for (int i = tid; i < n; i += 512) {
        int2 cv = binned[(size_t)bin * CAPB + i];
        int r = cv.x & (BIN_ROWS - 1);
        int c = (int)(((unsigned)cv.x) >> BIN_SHIFT);
        int slot = atomicAdd(&cnt_s[r], 1);
        if (slot < CAPR) {
            rowbuf[r * CAPR + slot] = make_int2(c, cv.y);
        } else if (slot < CAPR + CAPE) {
            ext[(size_t)(bin * BIN_ROWS + r) * CAPE + (slot - CAPR)] = make_int2(c, cv.y);
        }
        // slot >= CAPR+CAPE: dropped; rare_fix recomputes that row
    }
    __syncthreads();
    for (int r = tid; r < BIN_ROWS; r += 512) {
        if (cnt_s[r] > CAPR + CAPE) {
            int q = atomicAdd(rare_cnt, 1);
            if (q < RARE_MAX) rare[q] = bin * BIN_ROWS + r;
        }
    }
    int4* dst = (int4*)(buckets + (size_t)bin * BIN_ROWS * 32);
    for (int idx = tid; idx < BIN_ROWS * 8; idx += 512) {
        int r = idx >> 3, q = idx & 7;
        int4 o;
        if (q == 0) {
            int2 t = rowbuf[r * CAPR];
            o = make_int4(cnt_s[r], 0, t.x, t.y);        // full count (may exceed CAPR)
        } else {
            int2 a = rowbuf[r * CAPR + 2 * q - 1];
            int2 b = rowbuf[r * CAPR + 2 * q];
            o = make_int4(a.x, a.y, b.x, b.y);
        }
        dst[idx] = o;
    }
}

// ---------- SpMM gather (bf16): 16 lanes per row, 4 rows per wave ----------
__global__ void spmm_gather16(const int* __restrict__ buckets,
                              const int2* __restrict__ ext,
                              const ushortT* __restrict__ F,
                              ushortT* __restrict__ out) {
    int wv   = (blockIdx.x * blockDim.x + threadIdx.x) >> 6;
    int lane = threadIdx.x & 63;
    int l15  = lane & 15;
    int gb   = lane & 48;                                // group base lane (0,16,32,48)
    int r0   = wv << 2;
    if (r0 >= N_NODES) return;
    int row  = r0 + (lane >> 4);

    // 512B metadata load: 4 bucket rows, 16 int2 each
    int2 md = ((const int2*)(buckets + (size_t)r0 * 32))[lane];

    int cnt = __shfl(md.x, gb);                          // entry 0 of own group's row
    int nb  = (cnt < CAPR) ? cnt : CAPR;
    int net = cnt - CAPR;
    int ne  = (net < 0) ? 0 : ((net > CAPE) ? CAPE : net);

    uint2 f[CAPR];
#pragma unroll
    for (int k = 0; k < CAPR; ++k) {
        int cs = __shfl(md.x, gb + k + 1);
        int c  = (k < nb) ? cs : 0;
        f[k] = *(const uint2*)(F + ((size_t)c << 6) + (l15 << 2));
    }
    float4 acc = make_float4(0.f, 0.f, 0.f, 0.f);
#pragma unroll
    for (int k = 0; k < CAPR; ++k) {
        int vi = __shfl(md.y, gb + k + 1);
        float v = (k < nb) ? __int_as_float(vi) : 0.f;
        acc.x = fmaf(v, __uint_as_float(f[k].x << 16), acc.x);
        acc.y = fmaf(v, __uint_as_float(f[k].x & 0xFFFF0000u), acc.y);
        acc.z = fmaf(v, __uint_as_float(f[k].y << 16), acc.z);
        acc.w = fmaf(v, __uint_as_float(f[k].y & 0xFFFF0000u), acc.w);
    }

    if (__ballot(ne > 0)) {
        int2 ev = ext[((size_t)row << 3) + (l15 & 7)];
#pragma unroll
        for (int k = 0; k < CAPE; ++k) {
            int cs = __shfl(ev.x, gb + k);
            int vi = __shfl(ev.y, gb + k);
            int c  = (k < ne) ? cs : 0;
            float v = (k < ne) ? __int_as_float(vi) : 0.f;
            uint2 fw = *(const uint2*)(F + ((size_t)c << 6) + (l15 << 2));
            acc.x = fmaf(v, __uint_as_float(fw.x << 16), acc.x);
            acc.y = fmaf(v, __uint_as_float(fw.x & 0xFFFF0000u), acc.y);
            acc.z = fmaf(v, __uint_as_float(fw.y << 16), acc.z);
            acc.w = fmaf(v, __uint_as_float(fw.y & 0xFFFF0000u), acc.w);
        }
    }
    // deg>23 rows: partial written here, overwritten by rare_fix afterwards.

    *(uint2*)(out + ((size_t)row << 6) + (l15 << 2)) =
        make_uint2(pack2(acc.x, acc.y), pack2(acc.z, acc.w));
}

// ---------- rare rows (deg>23 or bin overflow): full recompute, one wave per row ----------
__global__ void rare_fix(const int* __restrict__ rare_cnt,
                         const int* __restrict__ rare,
                         const int* __restrict__ bin_cursor,
                         const int2* __restrict__ binned,
                         const int* __restrict__ g_cnt,
                         const int4* __restrict__ G,
                         const ushortT* __restrict__ F,
                         ushortT* __restrict__ out) {
    int lane = threadIdx.x & 63;
    int wv = (blockIdx.x * blockDim.x + threadIdx.x) >> 6;
    int nw = (gridDim.x * blockDim.x) >> 6;
    int n = *rare_cnt; if (n > RARE_MAX) n = RARE_MAX;
    for (int i = wv; i < n; i += nw) {
        int row = rare[i];
        int bin = row >> BIN_SHIFT, rloc = row & (BIN_ROWS - 1);
        int m = bin_cursor[bin]; if (m > CAPB) m = CAPB;
        size_t bb = (size_t)bin * CAPB;
        float acc = 0.f;
        for (int base = 0; base < m; base += 64) {
            int j = base + lane;
            int2 e = (j < m) ? binned[bb + j] : make_int2(0, 0);
            bool match = (j < m) && ((e.x & (BIN_ROWS - 1)) == rloc);
            unsigned long long mask = __ballot(match);
            while (mask) {
                int src = __ffsll(mask) - 1; mask &= mask - 1;
                int c = (int)(((unsigned)__shfl(e.x, src)) >> BIN_SHIFT);
                float v = __int_as_float(__shfl(e.y, src));
                acc = fmaf(v, bf2f(F[((size_t)c << 6) + lane]), acc);
            }
        }
        int gc = *g_cnt; if (gc > G_MAX) gc = G_MAX;
        for (int j = 0; j < gc; ++j) {
            int4 t = G[j];
            if (t.x == row)
                acc = fmaf(__int_as_float(t.z), bf2f(F[((size_t)t.y << 6) + lane]), acc);
        }
        out[((size_t)row << 6) + lane] = f2bf(acc);
    }
}

// ---------- prediction (bf16): 2 batch elements per thread for MLP ----------
__global__ void pred_bf16(const int* __restrict__ u_idx,
                          const int* __restrict__ i_idx,
                          const ushortT* __restrict__ F,
                          const float* __restrict__ bu,
                          const float* __restrict__ bi,
                          const float* __restrict__ mu,
                          float* __restrict__ out) {
    int gid = blockIdx.x * blockDim.x + threadIdx.x;
    int t = gid >> 4;
    int s = gid & 15;
    if (t >= BATCH / 2) return;
    int b0 = t, b1 = t + BATCH / 2;
    int u0 = u_idx[b0], i0 = i_idx[b0];
    int u1 = u_idx[b1], i1 = i_idx[b1];
    ushort4 a0 = *((const ushort4*)(F + ((size_t)u0 << 6)) + s);
    ushort4 c0 = *((const ushort4*)(F + ((size_t)(N_USERS + i0) << 6)) + s);
    ushort4 a1 = *((const ushort4*)(F + ((size_t)u1 << 6)) + s);
    ushort4 c1 = *((const ushort4*)(F + ((size_t)(N_USERS + i1) << 6)) + s);
    float p0 = bf2f(a0.x) * bf2f(c0.x) + bf2f(a0.y) * bf2f(c0.y)
             + bf2f(a0.z) * bf2f(c0.z) + bf2f(a0.w) * bf2f(c0.w);
    float p1 = bf2f(a1.x) * bf2f(c1.x) + bf2f(a1.y) * bf2f(c1.y)
             + bf2f(a1.z) * bf2f(c1.z) + bf2f(a1.w) * bf2f(c1.w);
    p0 += __shfl_xor(p0, 1); p1 += __shfl_xor(p1, 1);
    p0 += __shfl_xor(p0, 2); p1 += __shfl_xor(p1, 2);
    p0 += __shfl_xor(p0, 4); p1 += __shfl_xor(p1, 4);
    p0 += __shfl_xor(p0, 8); p1 += __shfl_xor(p1, 8);
    if (s == 0) {
        out[b0] = p0 + bu[u0] + bi[i0] + mu[0];
        out[b1] = p1 + bu[u1] + bi[i1] + mu[0];
    }
}

// ---------- f32 fallback (ws too small): edge-parallel atomics ----------
__global__ void spmm_scatter(const int* __restrict__ rows,
                             const int* __restrict__ cols,
                             const float* __restrict__ vals,
                             const float* __restrict__ Hu,
                             const float* __restrict__ Hi,
                             float* __restrict__ out) {
    int gid = blockIdx.x * blockDim.x + threadIdx.x;
    int e = gid >> 4;
    int s = gid & 15;
    if (e >= NNZ) return;
    int r = rows[e];
    int c = cols[e];
    float v = vals[e];
    const float* src = (c < N_USERS) ? (Hu + (size_t)c * DIM)
                                     : (Hi + (size_t)(c - N_USERS) * DIM);
    float4 x = *reinterpret_cast<const float4*>(src + s * 4);
    float* dst = out + (size_t)r * DIM + s * 4;
    atomicAdd(dst + 0, v * x.x);
    atomicAdd(dst + 1, v * x.y);
    atomicAdd(dst + 2, v * x.z);
    atomicAdd(dst + 3, v * x.w);
}

__global__ void pred_f32(const int* __restrict__ u_idx,
                         const int* __restrict__ i_idx,
                         const float* __restrict__ U,
                         const float* __restrict__ I,
                         const float* __restrict__ bu,
                         const float* __restrict__ bi,
                         const float* __restrict__ mu,
                         float* __restrict__ out) {
    int gid = blockIdx.x * blockDim.x + threadIdx.x;
    int b = gid >> 4;
    int s = gid & 15;
    if (b >= BATCH) return;
    int u = u_idx[b];
    int it = i_idx[b];
    float4 a = *reinterpret_cast<const float4*>(U + (size_t)u * DIM + s * 4);
    float4 c = *reinterpret_cast<const float4*>(I + (size_t)it * DIM + s * 4);
    float p = a.x * c.x + a.y * c.y + a.z * c.z + a.w * c.w;
    p += __shfl_xor(p, 1);
    p += __shfl_xor(p, 2);
    p += __shfl_xor(p, 4);
    p += __shfl_xor(p, 8);
    if (s == 0) out[b] = p + bu[u] + bi[it] + mu[0];
}

extern "C" void kernel_launch(void* const* d_in, const int* in_sizes, int n_in,
                              void* d_out, int out_size, void* d_ws, size_t ws_size,
                              hipStream_t stream) {
    const int*   u_idx  = (const int*)d_in[0];
    const int*   i_idx  = (const int*)d_in[1];
    const int*   A_rows = (const int*)d_in[2];
    const int*   A_cols = (const int*)d_in[3];
    const float* A_vals = (const float*)d_in[4];
    const float* Eu     = (const float*)d_in[5];
    const float* Ei     = (const float*)d_in[6];
    const float* bu     = (const float*)d_in[7];
    const float* bi     = (const float*)d_in[8];
    const float* mu     = (const float*)d_in[9];
    float* out = (float*)d_out;

    // ---- bf16-path workspace layout (bytes) ----
    char* ws = (char*)d_ws;
    ushortT* H1b       = (ushortT*)(ws);                    // 19,200,000
    ushortT* EbH2b     = (ushortT*)(ws + 19200000);         // 19,200,000 (Eb, then H2b)
    int*     buckets   = (int*)    (ws + 38400000);         // 19,202,048
    int2*    binned    = (int2*)   (ws + 57602048);         // 14,401,536 (1172*1536*8)
    int2*    ext       = (int2*)   (ws + 72003584);         //  9,601,024
    int*     bin_cursor= (int*)    (ws + 81604608);         //      4,864
    int*     g_cnt     = (int*)    (ws + 81609472);         //         32
    int*     rare_cnt  = (int*)    (ws + 81609504);         //         32
    int4*    G         = (int4*)   (ws + 81609536);         //    262,144
    int*     rare      = (int*)    (ws + 81871680);         //     16,384
    const size_t NEEDED = 81888064;

    const int pred_blocks   = ((BATCH / 2) * 16 + 255) / 256;
    const int gather_blocks = (N_NODES / 4) * 64 / 256;     // 9375 (4 rows per wave)

    if (ws_size >= NEEDED) {
        zero_ctrl<<<1, 1024, 0, stream>>>(bin_cursor, g_cnt, rare_cnt);
        fused_conv_p1<<<FUSED_BLOCKS, P1_THREADS, 0, stream>>>(
            (const float4*)Eu, (const float4*)Ei, (uint2*)EbH2b,
            A_rows, A_cols, A_vals, bin_cursor, binned, g_cnt, G, rare_cnt, rare);
        p2_fill<<<NBINS, 512, 0, stream>>>(bin_cursor, binned, buckets, ext, rare_cnt, rare);

        // Layer 1: H1b = A @ Eb
        spmm_gather16<<<gather_blocks, 256, 0, stream>>>(buckets, ext, EbH2b, H1b);
        rare_fix<<<32, 256, 0, stream>>>(rare_cnt, rare, bin_cursor, binned, g_cnt, G,
                                         EbH2b, H1b);
        // Layer 2: H2b = A @ H1b  (H2b overwrites Eb, dead after layer 1)
        spmm_gather16<<<gather_blocks, 256, 0, stream>>>(buckets, ext, H1b, EbH2b);
        rare_fix<<<32, 256, 0, stream>>>(rare_cnt, rare, bin_cursor, binned, g_cnt, G,
                                         H1b, EbH2b);

        pred_bf16<<<pred_blocks, 256, 0, stream>>>(u_idx, i_idx, EbH2b, bu, bi, mu, out);
    } else {
        // f32 fallback: edge-parallel atomics (needs 76.8 MB)
        float* H1 = (float*)d_ws;
        float* H2 = H1 + (size_t)N_NODES * DIM;
        const int n4 = 2 * N_NODES * DIM / 4;
        zero_ws<<<(n4 + 255) / 256, 256, 0, stream>>>((float4*)d_ws, n4);
        const int spmm_blocks = (NNZ * 16 + 255) / 256;
        spmm_scatter<<<spmm_blocks, 256, 0, stream>>>(A_rows, A_cols, A_vals, Eu, Ei, H1);
        spmm_scatter<<<spmm_blocks, 256, 0, stream>>>(A_rows, A_cols, A_vals,
                                                      H1, H1 + (size_t)N_USERS * DIM, H2);
        const int pf_blocks = (BATCH * 16 + 255) / 256;
        pred_f32<<<pf_blocks, 256, 0, stream>>>(u_idx, i_idx,
                                                H2, H2 + (size_t)N_USERS * DIM,
                                                bu, bi, mu, out);
    }
}

// Round 14
// 175.604 us; speedup vs baseline: 1.1974x; 1.1974x over previous
//
#include <hip/hip_runtime.h>

#define N_USERS 100000
#define N_ITEMS 50000
#define N_NODES 150000
#define NNZ 1500000
#define BATCH 1048576
#define DIM 64

#define BIN_SHIFT 7
#define BIN_ROWS 128
#define NBINS ((N_NODES + BIN_ROWS - 1) / BIN_ROWS)    // 1172
#define NROWS_PAD (NBINS * BIN_ROWS)                   // 150016
#define CAPB 1536                                      // per-bin edge capacity (mean 1280)
#define CAPR 15                                        // bucket entries per row (128B row)
#define CAPE 8                                         // ext entries per row (covers deg<=23)
#define P1_THREADS 1024
#define EPT 4
#define EPB (P1_THREADS * EPT)                         // 4096
#define P1_BLOCKS ((NNZ + EPB - 1) / EPB)              // 367
#define G_MAX 16384
#define RARE_MAX 4096

typedef unsigned short ushortT;

__device__ __forceinline__ float bf2f(ushortT x) {
    return __uint_as_float(((unsigned)x) << 16);
}
__device__ __forceinline__ ushortT f2bf(float x) {      // RNE
    unsigned u = __float_as_uint(x);
    return (ushortT)((u + 0x7FFFu + ((u >> 16) & 1u)) >> 16);
}
__device__ __forceinline__ unsigned pack2(float a, float b) {
    unsigned ua = __float_as_uint(a), ub = __float_as_uint(b);
    ua = (ua + 0x7FFFu + ((ua >> 16) & 1u)) >> 16;
    ub = (ub + 0x7FFFu + ((ub >> 16) & 1u)) >> 16;
    return ua | (ub << 16);
}

__global__ void zero_ws(float4* __restrict__ p, int n4) {
    int i = blockIdx.x * blockDim.x + threadIdx.x;
    if (i < n4) p[i] = make_float4(0.f, 0.f, 0.f, 0.f);
}

// ---------- convert [Eu;Ei] f32 -> bf16 table; block 0 also zeroes control structures ----------
__global__ void conv_E(const float4* __restrict__ Eu, const float4* __restrict__ Ei,
                       uint2* __restrict__ Eb,
                       int* __restrict__ bin_cursor, int* __restrict__ g_cnt,
                       int* __restrict__ rare_cnt) {
    if (blockIdx.x == 0) {
        for (int i = threadIdx.x; i < NBINS; i += 256) bin_cursor[i] = 0;
        if (threadIdx.x == 0) { *g_cnt = 0; *rare_cnt = 0; }
    }
    int i = blockIdx.x * blockDim.x + threadIdx.x;
    if (i >= (N_USERS + N_ITEMS) * DIM / 4) return;
    float4 x = (i < N_USERS * DIM / 4) ? Eu[i] : Ei[i - N_USERS * DIM / 4];
    Eb[i] = make_uint2(pack2(x.x, x.y), pack2(x.z, x.w));
}

// ---------- pass 1: bin edges; LDS-staged, bin-ordered COALESCED writeout (1024 thr) ----------
__global__ __launch_bounds__(P1_THREADS)
void p1_bin(const int* __restrict__ rows,
            const int* __restrict__ cols,
            const float* __restrict__ vals,
            int* __restrict__ bin_cursor,
            int2* __restrict__ binned,
            int* __restrict__ g_cnt,
            int4* __restrict__ G,
            int* __restrict__ rare_cnt,
            int* __restrict__ rare) {
    __shared__ int h[NBINS];                 // global chunk base per bin
    __shared__ int lcnt[NBINS];              // block-local count, then cursor
    __shared__ int lbase[NBINS + 1];         // block-local exclusive prefix
    __shared__ int2 stage[EPB];              // 32 KB, bin-ordered edges
    __shared__ ushortT sbin[EPB];            // 8 KB, bin id per staged edge
    int tid = threadIdx.x;
    for (int i = tid; i < NBINS; i += P1_THREADS) lcnt[i] = 0;
    __syncthreads();

    int base_e = blockIdx.x * EPB;
    int re[EPT]; int ce[EPT]; float ve[EPT];
#pragma unroll
    for (int k = 0; k < EPT; ++k) {
        int e = base_e + k * P1_THREADS + tid;
        if (e < NNZ) {
            re[k] = rows[e]; ce[k] = cols[e]; ve[k] = vals[e];
            atomicAdd(&lcnt[re[k] >> BIN_SHIFT], 1);
        } else {
            re[k] = -1; ce[k] = 0; ve[k] = 0.f;
        }
    }
    __syncthreads();

    // exclusive scan of lcnt -> lbase (wave 0: shfl inclusive scan + carry)
    if (tid < 64) {
        int carry = 0;
        for (int b0 = 0; b0 < NBINS; b0 += 64) {
            int idx = b0 + tid;
            int x = (idx < NBINS) ? lcnt[idx] : 0;
            int incl = x;
#pragma unroll
            for (int off = 1; off < 64; off <<= 1) {
                int t = __shfl_up(incl, off);
                if (tid >= off) incl += t;
            }
            if (idx < NBINS) lbase[idx] = carry + incl - x;
            carry += __shfl(incl, 63);
        }
        if (tid == 0) lbase[NBINS] = carry;
    }
    __syncthreads();

    // allocate global chunks; reset local cursors
    for (int i = tid; i < NBINS; i += P1_THREADS) {
        int c = lcnt[i];
        h[i] = (c > 0) ? atomicAdd(&bin_cursor[i], c) : 0;
        lcnt[i] = 0;
    }
    __syncthreads();

    // stage edges into LDS in bin-order
#pragma unroll
    for (int k = 0; k < EPT; ++k) {
        if (re[k] >= 0) {
            int b = re[k] >> BIN_SHIFT;
            int pos = lbase[b] + atomicAdd(&lcnt[b], 1);
            stage[pos] = make_int2((ce[k] << BIN_SHIFT) | (re[k] & (BIN_ROWS - 1)),
                                   __float_as_int(ve[k]));
            sbin[pos] = (ushortT)b;
        }
    }
    __syncthreads();

    // coalesced writeout: consecutive threads -> consecutive addresses per chunk
    int total = lbase[NBINS];
    for (int j = tid; j < total; j += P1_THREADS) {
        int b = sbin[j];
        int2 cv = stage[j];
        int off = h[b] + (j - lbase[b]);
        if (off < CAPB) {
            binned[(size_t)b * CAPB + off] = cv;
        } else {                                         // statistically impossible; correctness path
            int r = b * BIN_ROWS + (cv.x & (BIN_ROWS - 1));
            int c = (int)(((unsigned)cv.x) >> BIN_SHIFT);
            int p = atomicAdd(g_cnt, 1);
            if (p < G_MAX) G[p] = make_int4(r, c, cv.y, 0);
            int q = atomicAdd(rare_cnt, 1);
            if (q < RARE_MAX) rare[q] = r;
        }
    }
}

// ---------- pass 2: build 128 bucket rows (+ext) per bin in LDS (512 thr) ----------
// Row format (32 ints / 128 B): [cnt_full, pad, c0, v0, ..., c14, v14]
__global__ __launch_bounds__(512)
void p2_fill(const int* __restrict__ bin_cursor,
             const int2* __restrict__ binned,
             int* __restrict__ buckets,
             int2* __restrict__ ext,
             int* __restrict__ rare_cnt,
             int* __restrict__ rare) {
    __shared__ int  cnt_s[BIN_ROWS];                 // 0.5 KB
    __shared__ int2 rowbuf[BIN_ROWS * CAPR];         // 15 KB
    int bin = blockIdx.x, tid = threadIdx.x;
    for (int i = tid; i < BIN_ROWS; i += 512) cnt_s[i] = 0;
    __syncthreads();
    int n = bin_cursor[bin]; if (n > CAPB) n = CAPB;
    for (int i = tid; i < n; i += 512) {
        int2 cv = binned[(size_t)bin * CAPB + i];
        int r = cv.x & (BIN_ROWS - 1);
        int c = (int)(((unsigned)cv.x) >> BIN_SHIFT);
        int slot = atomicAdd(&cnt_s[r], 1);
        if (slot < CAPR) {
            rowbuf[r * CAPR + slot] = make_int2(c, cv.y);
        } else if (slot < CAPR + CAPE) {
            ext[(size_t)(bin * BIN_ROWS + r) * CAPE + (slot - CAPR)] = make_int2(c, cv.y);
        }
        // slot >= CAPR+CAPE: dropped; rare_fix recomputes that row
    }
    __syncthreads();
    for (int r = tid; r < BIN_ROWS; r += 512) {
        if (cnt_s[r] > CAPR + CAPE) {
            int q = atomicAdd(rare_cnt, 1);
            if (q < RARE_MAX) rare[q] = bin * BIN_ROWS + r;
        }
    }
    int4* dst = (int4*)(buckets + (size_t)bin * BIN_ROWS * 32);
    for (int idx = tid; idx < BIN_ROWS * 8; idx += 512) {
        int r = idx >> 3, q = idx & 7;
        int4 o;
        if (q == 0) {
            int2 t = rowbuf[r * CAPR];
            o = make_int4(cnt_s[r], 0, t.x, t.y);        // full count (may exceed CAPR)
        } else {
            int2 a = rowbuf[r * CAPR + 2 * q - 1];
            int2 b = rowbuf[r * CAPR + 2 * q];
            o = make_int4(a.x, a.y, b.x, b.y);
        }
        dst[idx] = o;
    }
}

// ---------- SpMM gather (bf16): 16 lanes per row, 4 rows per wave ----------
__global__ void spmm_gather16(const int* __restrict__ buckets,
                              const int2* __restrict__ ext,
                              const ushortT* __restrict__ F,
                              ushortT* __restrict__ out) {
    int wv   = (blockIdx.x * blockDim.x + threadIdx.x) >> 6;
    int lane = threadIdx.x & 63;
    int l15  = lane & 15;
    int gb   = lane & 48;                                // group base lane (0,16,32,48)
    int r0   = wv << 2;
    if (r0 >= N_NODES) return;
    int row  = r0 + (lane >> 4);

    // 512B metadata load: 4 bucket rows, 16 int2 each
    int2 md = ((const int2*)(buckets + (size_t)r0 * 32))[lane];

    int cnt = __shfl(md.x, gb);                          // entry 0 of own group's row
    int nb  = (cnt < CAPR) ? cnt : CAPR;
    int net = cnt - CAPR;
    int ne  = (net < 0) ? 0 : ((net > CAPE) ? CAPE : net);

    uint2 f[CAPR];
#pragma unroll
    for (int k = 0; k < CAPR; ++k) {
        int cs = __shfl(md.x, gb + k + 1);
        int c  = (k < nb) ? cs : 0;
        f[k] = *(const uint2*)(F + ((size_t)c << 6) + (l15 << 2));
    }
    float4 acc = make_float4(0.f, 0.f, 0.f, 0.f);
#pragma unroll
    for (int k = 0; k < CAPR; ++k) {
        int vi = __shfl(md.y, gb + k + 1);
        float v = (k < nb) ? __int_as_float(vi) : 0.f;
        acc.x = fmaf(v, __uint_as_float(f[k].x << 16), acc.x);
        acc.y = fmaf(v, __uint_as_float(f[k].x & 0xFFFF0000u), acc.y);
        acc.z = fmaf(v, __uint_as_float(f[k].y << 16), acc.z);
        acc.w = fmaf(v, __uint_as_float(f[k].y & 0xFFFF0000u), acc.w);
    }

    if (__ballot(ne > 0)) {
        int2 ev = ext[((size_t)row << 3) + (l15 & 7)];
#pragma unroll
        for (int k = 0; k < CAPE; ++k) {
            int cs = __shfl(ev.x, gb + k);
            int vi = __shfl(ev.y, gb + k);
            int c  = (k < ne) ? cs : 0;
            float v = (k < ne) ? __int_as_float(vi) : 0.f;
            uint2 fw = *(const uint2*)(F + ((size_t)c << 6) + (l15 << 2));
            acc.x = fmaf(v, __uint_as_float(fw.x << 16), acc.x);
            acc.y = fmaf(v, __uint_as_float(fw.x & 0xFFFF0000u), acc.y);
            acc.z = fmaf(v, __uint_as_float(fw.y << 16), acc.z);
            acc.w = fmaf(v, __uint_as_float(fw.y & 0xFFFF0000u), acc.w);
        }
    }
    // deg>23 rows: partial written here, overwritten by rare_fix afterwards.

    *(uint2*)(out + ((size_t)row << 6) + (l15 << 2)) =
        make_uint2(pack2(acc.x, acc.y), pack2(acc.z, acc.w));
}

// ---------- rare rows (deg>23 or bin overflow): full recompute, one wave per row ----------
__global__ void rare_fix(const int* __restrict__ rare_cnt,
                         const int* __restrict__ rare,
                         const int* __restrict__ bin_cursor,
                         const int2* __restrict__ binned,
                         const int* __restrict__ g_cnt,
                         const int4* __restrict__ G,
                         const ushortT* __restrict__ F,
                         ushortT* __restrict__ out) {
    int lane = threadIdx.x & 63;
    int wv = (blockIdx.x * blockDim.x + threadIdx.x) >> 6;
    int nw = (gridDim.x * blockDim.x) >> 6;
    int n = *rare_cnt; if (n > RARE_MAX) n = RARE_MAX;
    for (int i = wv; i < n; i += nw) {
        int row = rare[i];
        int bin = row >> BIN_SHIFT, rloc = row & (BIN_ROWS - 1);
        int m = bin_cursor[bin]; if (m > CAPB) m = CAPB;
        size_t bb = (size_t)bin * CAPB;
        float acc = 0.f;
        for (int base = 0; base < m; base += 64) {
            int j = base + lane;
            int2 e = (j < m) ? binned[bb + j] : make_int2(0, 0);
            bool match = (j < m) && ((e.x & (BIN_ROWS - 1)) == rloc);
            unsigned long long mask = __ballot(match);
            while (mask) {
                int src = __ffsll(mask) - 1; mask &= mask - 1;
                int c = (int)(((unsigned)__shfl(e.x, src)) >> BIN_SHIFT);
                float v = __int_as_float(__shfl(e.y, src));
                acc = fmaf(v, bf2f(F[((size_t)c << 6) + lane]), acc);
            }
        }
        int gc = *g_cnt; if (gc > G_MAX) gc = G_MAX;
        for (int j = 0; j < gc; ++j) {
            int4 t = G[j];
            if (t.x == row)
                acc = fmaf(__int_as_float(t.z), bf2f(F[((size_t)t.y << 6) + lane]), acc);
        }
        out[((size_t)row << 6) + lane] = f2bf(acc);
    }
}

// ---------- prediction (bf16): 2 batch elements per thread for MLP ----------
__global__ void pred_bf16(const int* __restrict__ u_idx,
                          const int* __restrict__ i_idx,
                          const ushortT* __restrict__ F,
                          const float* __restrict__ bu,
                          const float* __restrict__ bi,
                          const float* __restrict__ mu,
                          float* __restrict__ out) {
    int gid = blockIdx.x * blockDim.x + threadIdx.x;
    int t = gid >> 4;
    int s = gid & 15;
    if (t >= BATCH / 2) return;
    int b0 = t, b1 = t + BATCH / 2;
    int u0 = u_idx[b0], i0 = i_idx[b0];
    int u1 = u_idx[b1], i1 = i_idx[b1];
    ushort4 a0 = *((const ushort4*)(F + ((size_t)u0 << 6)) + s);
    ushort4 c0 = *((const ushort4*)(F + ((size_t)(N_USERS + i0) << 6)) + s);
    ushort4 a1 = *((const ushort4*)(F + ((size_t)u1 << 6)) + s);
    ushort4 c1 = *((const ushort4*)(F + ((size_t)(N_USERS + i1) << 6)) + s);
    float p0 = bf2f(a0.x) * bf2f(c0.x) + bf2f(a0.y) * bf2f(c0.y)
             + bf2f(a0.z) * bf2f(c0.z) + bf2f(a0.w) * bf2f(c0.w);
    float p1 = bf2f(a1.x) * bf2f(c1.x) + bf2f(a1.y) * bf2f(c1.y)
             + bf2f(a1.z) * bf2f(c1.z) + bf2f(a1.w) * bf2f(c1.w);
    p0 += __shfl_xor(p0, 1); p1 += __shfl_xor(p1, 1);
    p0 += __shfl_xor(p0, 2); p1 += __shfl_xor(p1, 2);
    p0 += __shfl_xor(p0, 4); p1 += __shfl_xor(p1, 4);
    p0 += __shfl_xor(p0, 8); p1 += __shfl_xor(p1, 8);
    if (s == 0) {
        out[b0] = p0 + bu[u0] + bi[i0] + mu[0];
        out[b1] = p1 + bu[u1] + bi[i1] + mu[0];
    }
}

// ---------- f32 fallback (ws too small): edge-parallel atomics ----------
__global__ void spmm_scatter(const int* __restrict__ rows,
                             const int* __restrict__ cols,
                             const float* __restrict__ vals,
                             const float* __restrict__ Hu,
                             const float* __restrict__ Hi,
                             float* __restrict__ out) {
    int gid = blockIdx.x * blockDim.x + threadIdx.x;
    int e = gid >> 4;
    int s = gid & 15;
    if (e >= NNZ) return;
    int r = rows[e];
    int c = cols[e];
    float v = vals[e];
    const float* src = (c < N_USERS) ? (Hu + (size_t)c * DIM)
                                     : (Hi + (size_t)(c - N_USERS) * DIM);
    float4 x = *reinterpret_cast<const float4*>(src + s * 4);
    float* dst = out + (size_t)r * DIM + s * 4;
    atomicAdd(dst + 0, v * x.x);
    atomicAdd(dst + 1, v * x.y);
    atomicAdd(dst + 2, v * x.z);
    atomicAdd(dst + 3, v * x.w);
}

__global__ void pred_f32(const int* __restrict__ u_idx,
                         const int* __restrict__ i_idx,
                         const float* __restrict__ U,
                         const float* __restrict__ I,
                         const float* __restrict__ bu,
                         const float* __restrict__ bi,
                         const float* __restrict__ mu,
                         float* __restrict__ out) {
    int gid = blockIdx.x * blockDim.x + threadIdx.x;
    int b = gid >> 4;
    int s = gid & 15;
    if (b >= BATCH) return;
    int u = u_idx[b];
    int it = i_idx[b];
    float4 a = *reinterpret_cast<const float4*>(U + (size_t)u * DIM + s * 4);
    float4 c = *reinterpret_cast<const float4*>(I + (size_t)it * DIM + s * 4);
    float p = a.x * c.x + a.y * c.y + a.z * c.z + a.w * c.w;
    p += __shfl_xor(p, 1);
    p += __shfl_xor(p, 2);
    p += __shfl_xor(p, 4);
    p += __shfl_xor(p, 8);
    if (s == 0) out[b] = p + bu[u] + bi[it] + mu[0];
}

extern "C" void kernel_launch(void* const* d_in, const int* in_sizes, int n_in,
                              void* d_out, int out_size, void* d_ws, size_t ws_size,
                              hipStream_t stream) {
    const int*   u_idx  = (const int*)d_in[0];
    const int*   i_idx  = (const int*)d_in[1];
    const int*   A_rows = (const int*)d_in[2];
    const int*   A_cols = (const int*)d_in[3];
    const float* A_vals = (const float*)d_in[4];
    const float* Eu     = (const float*)d_in[5];
    const float* Ei     = (const float*)d_in[6];
    const float* bu     = (const float*)d_in[7];
    const float* bi     = (const float*)d_in[8];
    const float* mu     = (const float*)d_in[9];
    float* out = (float*)d_out;

    // ---- bf16-path workspace layout (bytes) ----
    char* ws = (char*)d_ws;
    ushortT* H1b       = (ushortT*)(ws);                    // 19,200,000
    ushortT* EbH2b     = (ushortT*)(ws + 19200000);         // 19,200,000 (Eb, then H2b)
    int*     buckets   = (int*)    (ws + 38400000);         // 19,202,048
    int2*    binned    = (int2*)   (ws + 57602048);         // 14,401,536 (1172*1536*8)
    int2*    ext       = (int2*)   (ws + 72003584);         //  9,601,024
    int*     bin_cursor= (int*)    (ws + 81604608);         //      4,864
    int*     g_cnt     = (int*)    (ws + 81609472);         //         32
    int*     rare_cnt  = (int*)    (ws + 81609504);         //         32
    int4*    G         = (int4*)   (ws + 81609536);         //    262,144
    int*     rare      = (int*)    (ws + 81871680);         //     16,384
    const size_t NEEDED = 81888064;

    const int pred_blocks   = ((BATCH / 2) * 16 + 255) / 256;
    const int gather_blocks = (N_NODES / 4) * 64 / 256;     // 9375 (4 rows per wave)
    const int conv_blocks   = ((N_USERS + N_ITEMS) * DIM / 4 + 255) / 256;

    if (ws_size >= NEEDED) {
        conv_E<<<conv_blocks, 256, 0, stream>>>((const float4*)Eu, (const float4*)Ei,
                                                (uint2*)EbH2b, bin_cursor, g_cnt, rare_cnt);
        p1_bin<<<P1_BLOCKS, P1_THREADS, 0, stream>>>(A_rows, A_cols, A_vals,
                                                     bin_cursor, binned, g_cnt, G,
                                                     rare_cnt, rare);
        p2_fill<<<NBINS, 512, 0, stream>>>(bin_cursor, binned, buckets, ext, rare_cnt, rare);

        // Layer 1: H1b = A @ Eb
        spmm_gather16<<<gather_blocks, 256, 0, stream>>>(buckets, ext, EbH2b, H1b);
        rare_fix<<<32, 256, 0, stream>>>(rare_cnt, rare, bin_cursor, binned, g_cnt, G,
                                         EbH2b, H1b);
        // Layer 2: H2b = A @ H1b  (H2b overwrites Eb, dead after layer 1)
        spmm_gather16<<<gather_blocks, 256, 0, stream>>>(buckets, ext, H1b, EbH2b);
        rare_fix<<<32, 256, 0, stream>>>(rare_cnt, rare, bin_cursor, binned, g_cnt, G,
                                         H1b, EbH2b);

        pred_bf16<<<pred_blocks, 256, 0, stream>>>(u_idx, i_idx, EbH2b, bu, bi, mu, out);
    } else {
        // f32 fallback: edge-parallel atomics (needs 76.8 MB)
        float* H1 = (float*)d_ws;
        float* H2 = H1 + (size_t)N_NODES * DIM;
        const int n4 = 2 * N_NODES * DIM / 4;
        zero_ws<<<(n4 + 255) / 256, 256, 0, stream>>>((float4*)d_ws, n4);
        const int spmm_blocks = (NNZ * 16 + 255) / 256;
        spmm_scatter<<<spmm_blocks, 256, 0, stream>>>(A_rows, A_cols, A_vals, Eu, Ei, H1);
        spmm_scatter<<<spmm_blocks, 256, 0, stream>>>(A_rows, A_cols, A_vals,
                                                      H1, H1 + (size_t)N_USERS * DIM, H2);
        const int pf_blocks = (BATCH * 16 + 255) / 256;
        pred_f32<<<pf_blocks, 256, 0, stream>>>(u_idx, i_idx,
                                                H2, H2 + (size_t)N_USERS * DIM,
                                                bu, bi, mu, out);
    }
}